// Round 17
// baseline (97.383 us; speedup 1.0000x reference)
//
#include <hip/hip_runtime.h>

#define NROW 8192
#define MDIM 128
#define KLAB 16
#define NSLAB 64                     // 8192 / 128 supertile rows
#define NTILE (NSLAB*(NSLAB+1)/2)    // 2080 upper-tri supertiles
#define MARGINP2 288.0f              // (1.5*sqrt(128))^2: clamp bound, min folded into clamp

typedef __attribute__((ext_vector_type(8))) short  s16x8;
typedef __attribute__((ext_vector_type(4))) float  f32x4;

#if __has_builtin(__builtin_amdgcn_sqrtf)
#define FSQRT(x) __builtin_amdgcn_sqrtf(x)
#else
#define FSQRT(x) sqrtf(x)
#endif
#if __has_builtin(__builtin_amdgcn_rcpf)
#define FRCP(x) __builtin_amdgcn_rcpf(x)
#else
#define FRCP(x) (1.0f / (x))
#endif
#if __has_builtin(__builtin_amdgcn_fmed3f)
#define FCLAMP(x) __builtin_amdgcn_fmed3f((x), 0.0f, MARGINP2)
#else
#define FCLAMP(x) fminf(fmaxf((x), 0.0f), MARGINP2)
#endif

__device__ __forceinline__ unsigned short f2bf(float x) {
  unsigned u = __float_as_uint(x);            // RTNE bf16, inputs finite
  return (unsigned short)((u + 0x7FFFu + ((u >> 16) & 1u)) >> 16);
}

// Wave handles 4 rows: bf16 convert + sumsq + label mask, packed {sq, mask} float2.
__global__ void prep_kernel(const float* __restrict__ feat, const int* __restrict__ label,
                            unsigned short* __restrict__ fbf, float2* __restrict__ sqm) {
  int wv = threadIdx.x >> 6, lane = threadIdx.x & 63;
  int sub = lane >> 4, l16 = lane & 15;
  int row = blockIdx.x * 16 + wv * 4 + sub;
  const float* rp = feat + (size_t)row * MDIM + l16 * 8;
  float4 va = *reinterpret_cast<const float4*>(rp);
  float4 vb = *reinterpret_cast<const float4*>(rp + 4);
  s16x8 st;
  st[0]=(short)f2bf(va.x); st[1]=(short)f2bf(va.y); st[2]=(short)f2bf(va.z); st[3]=(short)f2bf(va.w);
  st[4]=(short)f2bf(vb.x); st[5]=(short)f2bf(vb.y); st[6]=(short)f2bf(vb.z); st[7]=(short)f2bf(vb.w);
  *reinterpret_cast<s16x8*>(fbf + (size_t)row * MDIM + l16 * 8) = st;
  float s = va.x*va.x + va.y*va.y + va.z*va.z + va.w*va.w
          + vb.x*vb.x + vb.y*vb.y + vb.z*vb.z + vb.w*vb.w;
  #pragma unroll
  for (int off = 8; off >= 1; off >>= 1) s += __shfl_xor(s, off);   // reduce within 16-lane row group
  int lab = label[((size_t)blockIdx.x * 16 + wv * 4) * KLAB + lane];
  unsigned long long bal = __ballot(lab > 0);
  if (l16 == 0) {
    int m = (int)(unsigned)((bal >> (sub * 16)) & 0xFFFFull);
    sqm[row] = make_float2(s, __int_as_float(m));
  }
}

// Block = 8 waves (4x2 grid) = one 128x128 supertile (bi<=bj). R10 skeleton EXACTLY
// (A+B slabs in 64KB LDS, XOR-swizzled, coalesced; launch_bounds(512,2)).
// Micro-cuts vs R10: packed {sq,mask} metadata (12 loads vs 24), npos hoisted as float
// (or+popc+cvt per elem -> one fsub), per-fj hoisted sqs/nsum, fused final reduction
// via completion ticket (saves the reduce launch). mfma layout verified R2 (absmax 0).
__global__ __launch_bounds__(512, 2) void pair_main(
    const unsigned short* __restrict__ fbf, const float2* __restrict__ sqm,
    float* __restrict__ part, int* __restrict__ ticket, float* __restrict__ out) {
  __shared__ char smem[65536];            // A slab [0,32K), B slab [32K,64K)
  __shared__ float bsum[8];
  __shared__ int lastFlag;
  __shared__ double wsumD[8];

  int bi = 0, rem = blockIdx.x;
  while (rem >= NSLAB - bi) { rem -= NSLAB - bi; bi++; }
  int bj = bi + rem;
  bool diag = (bi == bj);

  int wv = threadIdx.x >> 6, lane = threadIdx.x & 63;
  int l15 = lane & 15, lg = lane >> 4;
  int wr = wv >> 1, wc = wv & 1;          // 4x2 wave grid: 32 rows x 64 cols each

  // ---- stage both slabs: coalesced 16B/lane global loads -> swizzled ds_write_b128 ----
  {
    const char* gA = (const char*)(fbf + (size_t)bi * 128 * MDIM);
    const char* gB = (const char*)(fbf + (size_t)bj * 128 * MDIM);
    int sub = lane >> 4, c = lane & 15;
    #pragma unroll
    for (int t = 0; t < 4; t++) {
      int lr = wv * 16 + t * 4 + sub;                 // local row 0..127
      s16x8 va = *reinterpret_cast<const s16x8*>(gA + lr * 256 + c * 16);
      s16x8 vb = *reinterpret_cast<const s16x8*>(gB + lr * 256 + c * 16);
      int wck = c ^ (lr & 7);                         // XOR swizzle on 16B chunk index
      *reinterpret_cast<s16x8*>(smem + lr * 256 + wck * 16) = va;
      *reinterpret_cast<s16x8*>(smem + 32768 + lr * 256 + wck * 16) = vb;
    }
  }

  // ---- metadata: packed {sq, mask} float2 loads; npos hoisted as float ----
  float sqi[2][4], nif[2][4]; int mi[2][4];
  #pragma unroll
  for (int fi = 0; fi < 2; fi++)
    #pragma unroll
    for (int r = 0; r < 4; r++) {
      float2 v = sqm[bi * 128 + wr * 32 + fi * 16 + lg * 4 + r];    // C/D row = lg*4 + r
      sqi[fi][r] = v.x;
      int m = __float_as_int(v.y);
      mi[fi][r] = m; nif[fi][r] = (float)__popc(m);
    }
  float sqj[4], njf[4]; int mj[4];
  #pragma unroll
  for (int fj = 0; fj < 4; fj++) {
    float2 v = sqm[bj * 128 + wc * 64 + fj * 16 + l15];             // C/D col = l15
    sqj[fj] = v.x;
    int m = __float_as_int(v.y);
    mj[fj] = m; njf[fj] = (float)__popc(m);
  }

  __syncthreads();

  // ---- A fragments: this wave's 32 rows, whole K=128 (32 VGPR) ----
  s16x8 af[2][4];
  #pragma unroll
  for (int fi = 0; fi < 2; fi++)
    #pragma unroll
    for (int ks = 0; ks < 4; ks++) {
      int lr = wr * 32 + fi * 16 + l15;
      int rc = (ks * 4 + lg) ^ (lr & 7);
      af[fi][ks] = *reinterpret_cast<const s16x8*>(smem + lr * 256 + rc * 16);
    }

  float sum = 0.0f;

  #pragma unroll
  for (int fj = 0; fj < 4; fj++) {
    s16x8 B[4];
    #pragma unroll
    for (int ks = 0; ks < 4; ks++) {
      int lr = wc * 64 + fj * 16 + l15;
      int rc = (ks * 4 + lg) ^ (lr & 7);
      B[ks] = *reinterpret_cast<const s16x8*>(smem + 32768 + lr * 256 + rc * 16);
    }

    f32x4 acc[2];
    acc[0] = (f32x4){0.f,0.f,0.f,0.f}; acc[1] = (f32x4){0.f,0.f,0.f,0.f};
    #pragma unroll
    for (int ks = 0; ks < 4; ks++)
      #pragma unroll
      for (int fi = 0; fi < 2; fi++)
        acc[fi] = __builtin_amdgcn_mfma_f32_16x16x32_bf16(af[fi][ks], B[ks], acc[fi], 0, 0, 0);

    // per-fj hoists: sqs = sqi + sqj[fj], nsum = ni + nj[fj]
    float sqs[2][4], nsf[2][4];
    #pragma unroll
    for (int fi = 0; fi < 2; fi++)
      #pragma unroll
      for (int r = 0; r < 4; r++) {
        sqs[fi][r] = sqi[fi][r] + sqj[fj];
        nsf[fi][r] = nif[fi][r] + njf[fj];
      }

    #pragma unroll
    for (int fi = 0; fi < 2; fi++)
      #pragma unroll
      for (int r = 0; r < 4; r++) {
        float d2 = fmaf(-2.0f, acc[fi][r], sqs[fi][r]);
        float t  = FSQRT(FCLAMP(d2));
        int   ic = __popc(mi[fi][r] & mj[fj]);
        float icf = (float)ic;
        float w  = icf * FRCP(nsf[fi][r] - icf);      // union = ni+nj-inter
        w = (ic == 0) ? -1.0f : w;
        if (diag) {
          int il = wr * 32 + fi * 16 + lg * 4 + r;
          int jl = wc * 64 + fj * 16 + l15;
          w *= (jl > il) ? 2.0f : ((jl == il) ? 1.0f : 0.0f);
        }
        sum = fmaf(w, t, sum);
      }
  }

  #pragma unroll
  for (int off = 32; off >= 1; off >>= 1) sum += __shfl_xor(sum, off);
  if (lane == 0) bsum[wv] = sum;
  __syncthreads();
  if (threadIdx.x == 0) {
    float s = 0.f;
    #pragma unroll
    for (int w = 0; w < 8; w++) s += bsum[w];
    part[blockIdx.x] = diag ? s : 2.0f * s;
    __threadfence();                                  // publish part[] before ticket
    lastFlag = (atomicAdd(ticket, 1) == NTILE - 1);
  }
  __syncthreads();

  // ---- last block: fused final reduction (deterministic: one block, fixed order) ----
  if (lastFlag) {
    __threadfence();                                  // acquire all part[] stores
    int tid = threadIdx.x;
    double s = 0.0;
    for (int i = tid; i < NTILE; i += 512) s += (double)part[i];
    #pragma unroll
    for (int off = 32; off >= 1; off >>= 1) s += __shfl_xor(s, off);
    if (lane == 0) wsumD[wv] = s;
    __syncthreads();
    if (tid == 0) {
      double t = 0.0;
      #pragma unroll
      for (int w = 0; w < 8; w++) t += wsumD[w];
      // undo deferred scales: /sqrt(128) and /n^2
      out[0] = (float)(t * (1.0 / (11.313708498984760 * 67108864.0)));
    }
  }
}

extern "C" void kernel_launch(void* const* d_in, const int* in_sizes, int n_in,
                              void* d_out, int out_size, void* d_ws, size_t ws_size,
                              hipStream_t stream) {
  const float* feat  = (const float*)d_in[0];
  const int*   label = (const int*)d_in[1];
  char* ws = (char*)d_ws;
  int*            ticket = (int*)ws;                             // 4 B (256 reserved)
  float*          part   = (float*)(ws + 256);                   // 2080 floats (8448 reserved)
  float2*         sqm    = (float2*)(ws + 16384);                // 64 KB {sq, mask}
  unsigned short* fbf    = (unsigned short*)(ws + 16384 + 65536);// 2 MB bf16 feature
  float* out = (float*)d_out;

  (void)hipMemsetAsync(ticket, 0, sizeof(int), stream);
  prep_kernel<<<NROW / 16, 256, 0, stream>>>(feat, label, fbf, sqm);
  pair_main<<<NTILE, 512, 0, stream>>>(fbf, sqm, part, ticket, out);
}

// Round 18
// 57.860 us; speedup vs baseline: 1.6831x; 1.6831x over previous
//
#include <hip/hip_runtime.h>

#define NROW 8192
#define MDIM 128
#define KLAB 16
#define NSLAB 64                     // 8192 / 128 supertile rows
#define NTILE (NSLAB*(NSLAB+1)/2)    // 2080 upper-tri supertiles
#define MARGINP2 288.0f              // (1.5*sqrt(128))^2: clamp bound, min folded into clamp

typedef __attribute__((ext_vector_type(8))) short  s16x8;
typedef __attribute__((ext_vector_type(4))) float  f32x4;

#if __has_builtin(__builtin_amdgcn_sqrtf)
#define FSQRT(x) __builtin_amdgcn_sqrtf(x)
#else
#define FSQRT(x) sqrtf(x)
#endif
#if __has_builtin(__builtin_amdgcn_rcpf)
#define FRCP(x) __builtin_amdgcn_rcpf(x)
#else
#define FRCP(x) (1.0f / (x))
#endif
#if __has_builtin(__builtin_amdgcn_fmed3f)
#define FCLAMP(x) __builtin_amdgcn_fmed3f((x), 0.0f, MARGINP2)
#else
#define FCLAMP(x) fminf(fmaxf((x), 0.0f), MARGINP2)
#endif

__device__ __forceinline__ unsigned short f2bf(float x) {
  unsigned u = __float_as_uint(x);            // RTNE bf16, inputs finite
  return (unsigned short)((u + 0x7FFFu + ((u >> 16) & 1u)) >> 16);
}

// Wave handles 4 rows: bf16 convert + sumsq + label mask, packed {sq, mask} float2.
__global__ void prep_kernel(const float* __restrict__ feat, const int* __restrict__ label,
                            unsigned short* __restrict__ fbf, float2* __restrict__ sqm) {
  int wv = threadIdx.x >> 6, lane = threadIdx.x & 63;
  int sub = lane >> 4, l16 = lane & 15;
  int row = blockIdx.x * 16 + wv * 4 + sub;
  const float* rp = feat + (size_t)row * MDIM + l16 * 8;
  float4 va = *reinterpret_cast<const float4*>(rp);
  float4 vb = *reinterpret_cast<const float4*>(rp + 4);
  s16x8 st;
  st[0]=(short)f2bf(va.x); st[1]=(short)f2bf(va.y); st[2]=(short)f2bf(va.z); st[3]=(short)f2bf(va.w);
  st[4]=(short)f2bf(vb.x); st[5]=(short)f2bf(vb.y); st[6]=(short)f2bf(vb.z); st[7]=(short)f2bf(vb.w);
  *reinterpret_cast<s16x8*>(fbf + (size_t)row * MDIM + l16 * 8) = st;
  float s = va.x*va.x + va.y*va.y + va.z*va.z + va.w*va.w
          + vb.x*vb.x + vb.y*vb.y + vb.z*vb.z + vb.w*vb.w;
  #pragma unroll
  for (int off = 8; off >= 1; off >>= 1) s += __shfl_xor(s, off);   // reduce within 16-lane row group
  int lab = label[((size_t)blockIdx.x * 16 + wv * 4) * KLAB + lane];
  unsigned long long bal = __ballot(lab > 0);
  if (l16 == 0) {
    int m = (int)(unsigned)((bal >> (sub * 16)) & 0xFFFFull);
    sqm[row] = make_float2(s, __int_as_float(m));
  }
}

// Block = 8 waves (4x2 grid) = one 128x128 supertile (bi<=bj). R10 skeleton EXACTLY
// (A+B slabs in 64KB LDS, XOR-swizzled, coalesced; launch_bounds(512,2); three-launch
// flow, NO fences/atomics - R17's threadfence+ticket L2-invalidate cost 50 us).
// Micro-cuts vs R10 (register-local only): packed {sq,mask} metadata, npos hoisted as
// float (per-elem or+popc+cvt -> one fsub), per-fj hoisted sqs/nsum.
// mfma_f32_16x16x32_bf16 layout as verified in round 2 (absmax == 0).
__global__ __launch_bounds__(512, 2) void pair_main(
    const unsigned short* __restrict__ fbf, const float2* __restrict__ sqm,
    float* __restrict__ part) {
  __shared__ char smem[65536];            // A slab [0,32K), B slab [32K,64K)
  __shared__ float bsum[8];

  int bi = 0, rem = blockIdx.x;
  while (rem >= NSLAB - bi) { rem -= NSLAB - bi; bi++; }
  int bj = bi + rem;
  bool diag = (bi == bj);

  int wv = threadIdx.x >> 6, lane = threadIdx.x & 63;
  int l15 = lane & 15, lg = lane >> 4;
  int wr = wv >> 1, wc = wv & 1;          // 4x2 wave grid: 32 rows x 64 cols each

  // ---- stage both slabs: coalesced 16B/lane global loads -> swizzled ds_write_b128 ----
  {
    const char* gA = (const char*)(fbf + (size_t)bi * 128 * MDIM);
    const char* gB = (const char*)(fbf + (size_t)bj * 128 * MDIM);
    int sub = lane >> 4, c = lane & 15;
    #pragma unroll
    for (int t = 0; t < 4; t++) {
      int lr = wv * 16 + t * 4 + sub;                 // local row 0..127
      s16x8 va = *reinterpret_cast<const s16x8*>(gA + lr * 256 + c * 16);
      s16x8 vb = *reinterpret_cast<const s16x8*>(gB + lr * 256 + c * 16);
      int wck = c ^ (lr & 7);                         // XOR swizzle on 16B chunk index
      *reinterpret_cast<s16x8*>(smem + lr * 256 + wck * 16) = va;
      *reinterpret_cast<s16x8*>(smem + 32768 + lr * 256 + wck * 16) = vb;
    }
  }

  // ---- metadata: packed {sq, mask} float2 loads; npos hoisted as float ----
  float sqi[2][4], nif[2][4]; int mi[2][4];
  #pragma unroll
  for (int fi = 0; fi < 2; fi++)
    #pragma unroll
    for (int r = 0; r < 4; r++) {
      float2 v = sqm[bi * 128 + wr * 32 + fi * 16 + lg * 4 + r];    // C/D row = lg*4 + r
      sqi[fi][r] = v.x;
      int m = __float_as_int(v.y);
      mi[fi][r] = m; nif[fi][r] = (float)__popc(m);
    }
  float sqj[4], njf[4]; int mj[4];
  #pragma unroll
  for (int fj = 0; fj < 4; fj++) {
    float2 v = sqm[bj * 128 + wc * 64 + fj * 16 + l15];             // C/D col = l15
    sqj[fj] = v.x;
    int m = __float_as_int(v.y);
    mj[fj] = m; njf[fj] = (float)__popc(m);
  }

  __syncthreads();

  // ---- A fragments: this wave's 32 rows, whole K=128 (32 VGPR) ----
  s16x8 af[2][4];
  #pragma unroll
  for (int fi = 0; fi < 2; fi++)
    #pragma unroll
    for (int ks = 0; ks < 4; ks++) {
      int lr = wr * 32 + fi * 16 + l15;
      int rc = (ks * 4 + lg) ^ (lr & 7);
      af[fi][ks] = *reinterpret_cast<const s16x8*>(smem + lr * 256 + rc * 16);
    }

  float sum = 0.0f;

  #pragma unroll
  for (int fj = 0; fj < 4; fj++) {
    s16x8 B[4];
    #pragma unroll
    for (int ks = 0; ks < 4; ks++) {
      int lr = wc * 64 + fj * 16 + l15;
      int rc = (ks * 4 + lg) ^ (lr & 7);
      B[ks] = *reinterpret_cast<const s16x8*>(smem + 32768 + lr * 256 + rc * 16);
    }

    f32x4 acc[2];
    acc[0] = (f32x4){0.f,0.f,0.f,0.f}; acc[1] = (f32x4){0.f,0.f,0.f,0.f};
    #pragma unroll
    for (int ks = 0; ks < 4; ks++)
      #pragma unroll
      for (int fi = 0; fi < 2; fi++)
        acc[fi] = __builtin_amdgcn_mfma_f32_16x16x32_bf16(af[fi][ks], B[ks], acc[fi], 0, 0, 0);

    // per-fj hoists: sqs = sqi + sqj[fj], nsum = ni + nj[fj]
    float sqs[2][4], nsf[2][4];
    #pragma unroll
    for (int fi = 0; fi < 2; fi++)
      #pragma unroll
      for (int r = 0; r < 4; r++) {
        sqs[fi][r] = sqi[fi][r] + sqj[fj];
        nsf[fi][r] = nif[fi][r] + njf[fj];
      }

    #pragma unroll
    for (int fi = 0; fi < 2; fi++)
      #pragma unroll
      for (int r = 0; r < 4; r++) {
        float d2 = fmaf(-2.0f, acc[fi][r], sqs[fi][r]);
        float t  = FSQRT(FCLAMP(d2));
        int   ic = __popc(mi[fi][r] & mj[fj]);
        float icf = (float)ic;
        float w  = icf * FRCP(nsf[fi][r] - icf);      // union = ni+nj-inter
        w = (ic == 0) ? -1.0f : w;
        if (diag) {
          int il = wr * 32 + fi * 16 + lg * 4 + r;
          int jl = wc * 64 + fj * 16 + l15;
          w *= (jl > il) ? 2.0f : ((jl == il) ? 1.0f : 0.0f);
        }
        sum = fmaf(w, t, sum);
      }
  }

  #pragma unroll
  for (int off = 32; off >= 1; off >>= 1) sum += __shfl_xor(sum, off);
  if (lane == 0) bsum[wv] = sum;
  __syncthreads();
  if (threadIdx.x == 0) {
    float s = 0.f;
    #pragma unroll
    for (int w = 0; w < 8; w++) s += bsum[w];
    part[blockIdx.x] = diag ? s : 2.0f * s;   // one plain store per block, no atomics
  }
}

// Single block: sum 2080 partials (double accum) + apply deferred scales.
__global__ void reduce_kernel(const float* __restrict__ part, float* __restrict__ out) {
  int tid = threadIdx.x;
  double s = 0.0;
  for (int i = tid; i < NTILE; i += 256) s += (double)part[i];
  #pragma unroll
  for (int off = 32; off >= 1; off >>= 1) s += __shfl_xor(s, off);
  __shared__ double wsum[4];
  int wv = tid >> 6, lane = tid & 63;
  if (lane == 0) wsum[wv] = s;
  __syncthreads();
  if (tid == 0) {
    double t = wsum[0] + wsum[1] + wsum[2] + wsum[3];
    // undo deferred scales: /sqrt(128) and /n^2
    out[0] = (float)(t * (1.0 / (11.313708498984760 * 67108864.0)));
  }
}

extern "C" void kernel_launch(void* const* d_in, const int* in_sizes, int n_in,
                              void* d_out, int out_size, void* d_ws, size_t ws_size,
                              hipStream_t stream) {
  const float* feat  = (const float*)d_in[0];
  const int*   label = (const int*)d_in[1];
  char* ws = (char*)d_ws;
  float*          part = (float*)ws;                            // 2080 floats (16384 reserved)
  float2*         sqm  = (float2*)(ws + 16384);                 // 64 KB {sq, mask}
  unsigned short* fbf  = (unsigned short*)(ws + 16384 + 65536); // 2 MB bf16 feature
  float* out = (float*)d_out;

  prep_kernel<<<NROW / 16, 256, 0, stream>>>(feat, label, fbf, sqm);
  pair_main<<<NTILE, 512, 0, stream>>>(fbf, sqm, part);
  reduce_kernel<<<1, 256, 0, stream>>>(part, out);
}